// Round 3
// baseline (438.824 us; speedup 1.0000x reference)
//
#include <hip/hip_runtime.h>
#include <math.h>

#define BATCH 32768
#define NCLS  1000
#define NV4   250          // NCLS / 4
#define ALPHA 0.1f

// One wave (64 lanes) per row. Block = 256 threads = 4 waves.
// Rows 0..B-1: outputs (CE + distance term). Rows B..3B-1: classifier heads (CE only).
__global__ __launch_bounds__(256, 4) void loss_kernel(
    const float* __restrict__ outputs,      // [B, C]
    const float* __restrict__ oc,           // [2, B, C]
    const int*   __restrict__ labels,       // [B]
    const float* __restrict__ wb,           // [3]
    const float* __restrict__ ab,           // [1]
    const float* __restrict__ ag,           // [1]
    float* __restrict__ out)                // [1]
{
    const int lane  = threadIdx.x & 63;
    const int wave  = threadIdx.x >> 6;
    const int gwave = blockIdx.x * 4 + wave;
    const int nwav  = gridDim.x * 4;

    const float th1 = wb[0], th2 = wb[1], bb = wb[2];
    const float bias = ab[0], gamma = ag[0];
    const float inv_norm = 1.0f / sqrtf(th1 * th1 + th2 * th2);
    const float invB = 1.0f / (float)BATCH;

    float acc = 0.0f;   // uniform across the wave (all reductions are butterflies)

    const int R = 3 * BATCH;
    for (int row = gwave; row < R; row += nwav) {
        const bool is_out = (row < BATCH);
        const float* base;
        int lbl_idx;
        if (is_out) {
            base = outputs + (size_t)row * NCLS;
            lbl_idx = row;
        } else {
            const int r2 = row - BATCH;
            base = oc + (size_t)r2 * NCLS;
            lbl_idx = (r2 >= BATCH) ? (r2 - BATCH) : r2;
        }
        const int label = labels[lbl_idx];
        const float4* p = (const float4*)base;

        // Load the whole row into registers: lane covers float4 idx {lane, lane+64, lane+128, lane+192}
        float v[16];
        #pragma unroll
        for (int j = 0; j < 4; ++j) {
            const int idx = lane + j * 64;
            float4 q;
            if (idx < NV4) q = p[idx];
            else           q = make_float4(-INFINITY, -INFINITY, -INFINITY, -INFINITY);
            v[4 * j + 0] = q.x; v[4 * j + 1] = q.y;
            v[4 * j + 2] = q.z; v[4 * j + 3] = q.w;
        }

        // row max
        float m = v[0];
        #pragma unroll
        for (int j = 1; j < 16; ++j) m = fmaxf(m, v[j]);
        #pragma unroll
        for (int off = 32; off; off >>= 1) m = fmaxf(m, __shfl_xor(m, off, 64));

        // sum exp(v - m)
        float s = 0.0f;
        #pragma unroll
        for (int j = 0; j < 16; ++j) s += __expf(v[j] - m);
        #pragma unroll
        for (int off = 32; off; off >>= 1) s += __shfl_xor(s, off, 64);

        const float lse = m + __logf(s);
        const float x = base[label];           // uniform scalar load
        float contrib = (lse - x) * invB;      // cross-entropy term (mean over B)

        if (is_out) {
            // per-lane top-2, then butterfly merge
            float t0 = -INFINITY, t1 = -INFINITY;
            #pragma unroll
            for (int j = 0; j < 16; ++j) {
                const float val = v[j];
                if (val > t0)      { t1 = t0; t0 = val; }
                else if (val > t1) { t1 = val; }
            }
            #pragma unroll
            for (int off = 32; off; off >>= 1) {
                const float o0 = __shfl_xor(t0, off, 64);
                const float o1 = __shfl_xor(t1, off, 64);
                const float n0 = fmaxf(t0, o0);
                const float n1 = fmaxf(fminf(t0, o0), fmaxf(t1, o1));
                t0 = n0; t1 = n1;
            }
            // remove the first top-2 entry equal to x
            const float y = (t0 == x) ? t1 : ((t1 == x) ? t0 : (t0 + t1));
            const float dist = (th1 * x + th2 * y + bb - bias) * inv_norm;
            const float per = (dist >= 10.0f) ? -2.0f
                            : ((dist >= 0.0f) ? (-gamma * dist) : (-dist));
            contrib += ALPHA * per;
        }
        acc += contrib;
    }

    // block reduce: one partial per wave, one atomic per block
    __shared__ float wacc[4];
    if (lane == 0) wacc[wave] = acc;
    __syncthreads();
    if (threadIdx.x == 0) {
        float t = wacc[0] + wacc[1] + wacc[2] + wacc[3];
        atomicAdd(out, t);
    }
}

extern "C" void kernel_launch(void* const* d_in, const int* in_sizes, int n_in,
                              void* d_out, int out_size, void* d_ws, size_t ws_size,
                              hipStream_t stream) {
    const float* outputs = (const float*)d_in[0];
    const float* oc      = (const float*)d_in[1];
    const int*   labels  = (const int*)d_in[2];
    const float* wb      = (const float*)d_in[3];
    const float* ab      = (const float*)d_in[4];
    const float* ag      = (const float*)d_in[5];
    float* out = (float*)d_out;

    hipMemsetAsync(out, 0, (size_t)out_size * sizeof(float), stream);  // d_out is poisoned before every launch
    loss_kernel<<<dim3(2048), dim3(256), 0, stream>>>(outputs, oc, labels, wb, ab, ag, out);
}

// Round 4
// 434.050 us; speedup vs baseline: 1.0110x; 1.0110x over previous
//
#include <hip/hip_runtime.h>
#include <math.h>

#define BATCH 32768
#define NCLS  1000
#define NV4   250            // NCLS / 4
#define ALPHA 0.1f
#define GRID  2048
#define NWAVE (GRID * 4)     // 8192 waves; 3*BATCH / NWAVE = 12 rows per wave exactly
#define NROWS 12

struct Scalars {
    float th1, th2, bb, bias, gamma, inv_norm, invB;
};

// Row I (0..11) for wave `gwave` (< NWAVE): I<4 -> outputs rows, I>=4 -> classifier rows.
template <int I>
__device__ __forceinline__ void row_meta(int gwave,
                                         const float* __restrict__ outputs,
                                         const float* __restrict__ oc,
                                         const int* __restrict__ labels,
                                         const float*& base, int& label) {
    if constexpr (I < 4) {
        const int r = gwave + I * NWAVE;          // < BATCH
        base = outputs + (size_t)r * NCLS;
        label = labels[r];
    } else {
        const int r2 = gwave + (I - 4) * NWAVE;   // row into oc, in [0, 2*BATCH)
        base = oc + (size_t)r2 * NCLS;
        label = labels[(I < 8) ? r2 : (gwave + (I - 8) * NWAVE)];
    }
}

__device__ __forceinline__ void load_row(float (&v)[16], float& x,
                                         const float* __restrict__ base, int label, int lane) {
    const float4* p = (const float4*)base;
    #pragma unroll
    for (int j = 0; j < 4; ++j) {
        const int idx = lane + j * 64;
        float4 q;
        if (idx < NV4) q = p[idx];
        else           q = make_float4(-INFINITY, -INFINITY, -INFINITY, -INFINITY);
        v[4 * j + 0] = q.x; v[4 * j + 1] = q.y;
        v[4 * j + 2] = q.z; v[4 * j + 3] = q.w;
    }
    x = base[label];   // issued with the row loads; uniform; L1/L2 hit by reduce time
}

template <bool IS_OUT>
__device__ __forceinline__ float process_row(const float (&v)[16], float x, const Scalars& sc) {
    float m, contrib;
    if constexpr (IS_OUT) {
        // top-2 butterfly; t0 doubles as the row max
        float t0 = -INFINITY, t1 = -INFINITY;
        #pragma unroll
        for (int j = 0; j < 16; ++j) {
            const float val = v[j];
            const float nt1 = fmaxf(t1, fminf(t0, val));
            t0 = fmaxf(t0, val);
            t1 = nt1;
        }
        #pragma unroll
        for (int off = 32; off; off >>= 1) {
            const float o0 = __shfl_xor(t0, off, 64);
            const float o1 = __shfl_xor(t1, off, 64);
            const float n1 = fmaxf(fminf(t0, o0), fmaxf(t1, o1));
            t0 = fmaxf(t0, o0);
            t1 = n1;
        }
        m = t0;
        float s = 0.0f;
        #pragma unroll
        for (int j = 0; j < 16; ++j) s += __expf(v[j] - m);
        #pragma unroll
        for (int off = 32; off; off >>= 1) s += __shfl_xor(s, off, 64);
        const float lse = m + __logf(s);
        contrib = (lse - x) * sc.invB;
        // remove the FIRST top-2 entry equal to x
        const float y = (t0 == x) ? t1 : ((t1 == x) ? t0 : (t0 + t1));
        const float dist = (sc.th1 * x + sc.th2 * y + sc.bb - sc.bias) * sc.inv_norm;
        const float per = (dist >= 10.0f) ? -2.0f
                        : ((dist >= 0.0f) ? (-sc.gamma * dist) : (-dist));
        contrib += ALPHA * per;
    } else {
        m = v[0];
        #pragma unroll
        for (int j = 1; j < 16; ++j) m = fmaxf(m, v[j]);
        #pragma unroll
        for (int off = 32; off; off >>= 1) m = fmaxf(m, __shfl_xor(m, off, 64));
        float s = 0.0f;
        #pragma unroll
        for (int j = 0; j < 16; ++j) s += __expf(v[j] - m);
        #pragma unroll
        for (int off = 32; off; off >>= 1) s += __shfl_xor(s, off, 64);
        const float lse = m + __logf(s);
        contrib = (lse - x) * sc.invB;
    }
    return contrib;
}

// 2-deep pipelined walk over the 12 rows: prefetch row I+1 while reducing row I.
// Ping-pong via swapped references (all register indexing is compile-time).
template <int I>
__device__ __forceinline__ void step(float (&cur)[16], float& xcur,
                                     float (&nxt)[16], float& xnxt,
                                     float& acc, int gwave, int lane,
                                     const float* __restrict__ outputs,
                                     const float* __restrict__ oc,
                                     const int* __restrict__ labels,
                                     const Scalars& sc) {
    if constexpr (I + 1 < NROWS) {
        const float* b; int l;
        row_meta<I + 1>(gwave, outputs, oc, labels, b, l);
        load_row(nxt, xnxt, b, l, lane);
    }
    acc += process_row<(I < 4)>(cur, xcur, sc);
    if constexpr (I + 1 < NROWS) {
        step<I + 1>(nxt, xnxt, cur, xcur, acc, gwave, lane, outputs, oc, labels, sc);
    }
}

__global__ __launch_bounds__(256, 4) void loss_kernel(
    const float* __restrict__ outputs,      // [B, C]
    const float* __restrict__ oc,           // [2, B, C]
    const int*   __restrict__ labels,       // [B]
    const float* __restrict__ wb,           // [3]
    const float* __restrict__ ab,           // [1]
    const float* __restrict__ ag,           // [1]
    float* __restrict__ out)                // [1]
{
    const int lane  = threadIdx.x & 63;
    const int wave  = threadIdx.x >> 6;
    const int gwave = blockIdx.x * 4 + wave;

    Scalars sc;
    sc.th1 = wb[0]; sc.th2 = wb[1]; sc.bb = wb[2];
    sc.bias = ab[0]; sc.gamma = ag[0];
    sc.inv_norm = 1.0f / sqrtf(sc.th1 * sc.th1 + sc.th2 * sc.th2);
    sc.invB = 1.0f / (float)BATCH;

    float acc = 0.0f;
    float v[16], w[16];
    float xv = 0.0f, xw = 0.0f;

    {
        const float* b; int l;
        row_meta<0>(gwave, outputs, oc, labels, b, l);
        load_row(v, xv, b, l, lane);
    }
    step<0>(v, xv, w, xw, acc, gwave, lane, outputs, oc, labels, sc);

    // block reduce: one partial per wave, one atomic per block
    __shared__ float wacc[4];
    if (lane == 0) wacc[wave] = acc;
    __syncthreads();
    if (threadIdx.x == 0) {
        float t = wacc[0] + wacc[1] + wacc[2] + wacc[3];
        atomicAdd(out, t);
    }
}

extern "C" void kernel_launch(void* const* d_in, const int* in_sizes, int n_in,
                              void* d_out, int out_size, void* d_ws, size_t ws_size,
                              hipStream_t stream) {
    const float* outputs = (const float*)d_in[0];
    const float* oc      = (const float*)d_in[1];
    const int*   labels  = (const int*)d_in[2];
    const float* wb      = (const float*)d_in[3];
    const float* ab      = (const float*)d_in[4];
    const float* ag      = (const float*)d_in[5];
    float* out = (float*)d_out;

    hipMemsetAsync(out, 0, (size_t)out_size * sizeof(float), stream);  // d_out is poisoned before every launch
    loss_kernel<<<dim3(GRID), dim3(256), 0, stream>>>(outputs, oc, labels, wb, ab, ag, out);
}